// Round 2
// baseline (239.622 us; speedup 1.0000x reference)
//
#include <hip/hip_runtime.h>
#include <math.h>

// CBOW hierarchical-softmax loss.
//   B=65536 examples, C=10 context words, D=18 path nodes, E=128 embed dim.
//   loss[b] = -sum_d log( p_d + 1e-9 ),  p_d = (code==1) ? s_d : 1 - s_d,
//   s_d = sigmoid(u_d . v),  v = mean_c in_embed[ctx[b,c]].
//
// NOTE: p must be computed EXACTLY as the fp32 reference does (s then 1-s),
// including the catastrophic cancellation when s saturates to 1.0f — the
// "stable" sigmoid(-x) identity diverges from the reference by up to ~4 per
// term in the saturated tail (round 1 post-mortem: absmax 3.5 from this).
//
// One 64-lane wave per example; lane i holds row elements {2i,2i+1} (float2),
// so each row gather is one coalesced 512B wave load. 4 waves / 256-thread
// block, grid = B/4.

constexpr int Bn = 65536;
constexpr int Cn = 10;
constexpr int Dn = 18;
constexpr int En = 128;
constexpr float EPS = 1e-9f;

__global__ __launch_bounds__(256) void cbow_hs_kernel(
    const int* __restrict__ ctx,          // [B,C]
    const int* __restrict__ nodes,        // [B,D]
    const int* __restrict__ codes,        // [B,D]
    const float* __restrict__ in_embed,   // [V,E]
    const float* __restrict__ node_embed, // [N,E]
    float* __restrict__ out)              // [B]
{
    const int wave = threadIdx.x >> 6;   // 0..3
    const int lane = threadIdx.x & 63;
    const int b = (blockIdx.x << 2) + wave;

    const float2* __restrict__ in2 = (const float2*)in_embed;
    const float2* __restrict__ ne2 = (const float2*)node_embed;

    // ---- v = mean of context embeddings (each lane: 2 elements) ----
    // Load all indices first so the 10 row-gathers can be in flight together.
    int cidx[Cn];
    #pragma unroll
    for (int c = 0; c < Cn; ++c) cidx[c] = ctx[b * Cn + c];

    float2 v = make_float2(0.f, 0.f);
    #pragma unroll
    for (int c = 0; c < Cn; ++c) {
        float2 e = in2[(size_t)cidx[c] * (En / 2) + lane];
        v.x += e.x;
        v.y += e.y;
    }
    v.x *= (1.0f / Cn);
    v.y *= (1.0f / Cn);

    // ---- path-node dots + loss ----
    int nidx[Dn], code[Dn];
    #pragma unroll
    for (int d = 0; d < Dn; ++d) {
        nidx[d] = nodes[b * Dn + d];
        code[d] = codes[b * Dn + d];
    }

    // Partial dot per lane for all 18 nodes (loads pipeline across d).
    float pd[Dn];
    #pragma unroll
    for (int d = 0; d < Dn; ++d) {
        float2 u = ne2[(size_t)nidx[d] * (En / 2) + lane];
        pd[d] = u.x * v.x + u.y * v.y;
    }

    float loss = 0.f;
    #pragma unroll
    for (int d = 0; d < Dn; ++d) {
        float logit = pd[d];
        #pragma unroll
        for (int off = 32; off >= 1; off >>= 1)
            logit += __shfl_xor(logit, off, 64);
        // Literal fp32 reference semantics (precise expf/logf, s then 1-s):
        float s = 1.0f / (1.0f + expf(-logit));
        float p = (code[d] == 1) ? s : 1.0f - s;
        loss -= logf(p + EPS);
    }

    if (lane == 0) out[b] = loss;
}

extern "C" void kernel_launch(void* const* d_in, const int* in_sizes, int n_in,
                              void* d_out, int out_size, void* d_ws, size_t ws_size,
                              hipStream_t stream) {
    const int*   ctx        = (const int*)d_in[0];
    const int*   path_nodes = (const int*)d_in[1];
    const int*   codes      = (const int*)d_in[2];
    const float* in_embed   = (const float*)d_in[3];
    const float* node_embed = (const float*)d_in[4];
    float*       out        = (float*)d_out;

    dim3 grid(Bn / 4);
    dim3 block(256);
    cbow_hs_kernel<<<grid, block, 0, stream>>>(ctx, path_nodes, codes,
                                               in_embed, node_embed, out);
}

// Round 3
// 231.834 us; speedup vs baseline: 1.0336x; 1.0336x over previous
//
#include <hip/hip_runtime.h>
#include <math.h>

// CBOW hierarchical-softmax loss — R3: float4 gathers, half-wave d-split.
//   B=65536, C=10, D=18, E=128.
//   loss[b] = -sum_d log( p_d + 1e-9 ), p_d = (code==1) ? s_d : 1 - s_d,
//   s_d = sigmoid(u_d . v), v = mean_c in_embed[ctx[b,c]].
//
// R1 lesson: p MUST be computed literally as fp32 reference does (s, then
// 1-s) including cancellation at s==1.0f; precise expf/logf (not __expf).
// R2 lesson: VALU-bound (VALUBusy 86%, HBM 41%). Dominators: 108 butterfly
// shfl+adds and 18 redundant transcendental passes per wave.
//
// New layout: one wave per example; lanes 0-31 = half 0, 32-63 = half 1.
// Each row (128 f32 = 32 float4) is read by ONE 32-lane half as float4;
// the two halves gather DIFFERENT rows in the same instruction:
//   half 0 handles even c/d, half 1 odd. => 14 gather insts (was 28),
//   5-level butterflies within a half for 9 dots each (45 pairs, was 108),
//   9 transcendental passes (was 18).

constexpr int Bn = 65536;
constexpr int Cn = 10;
constexpr int Dn = 18;
constexpr float EPS = 1e-9f;

__global__ __launch_bounds__(256) void cbow_hs_kernel(
    const int* __restrict__ ctx,          // [B,C]
    const int* __restrict__ nodes,        // [B,D]
    const int* __restrict__ codes,        // [B,D]
    const float* __restrict__ in_embed,   // [V,E]
    const float* __restrict__ node_embed, // [N,E]
    float* __restrict__ out)              // [B]
{
    const int wave = threadIdx.x >> 6;   // 0..3
    const int lane = threadIdx.x & 63;
    const int sl   = lane & 31;          // sub-lane within half
    const bool hi  = lane >= 32;         // which half
    const int b = (blockIdx.x << 2) + wave;

    // ---- index preload, vectorized int2 (40B / 72B row strides are 8B-aligned)
    int cidx[Cn];
    const int2* c2 = (const int2*)(ctx + b * Cn);
    #pragma unroll
    for (int k = 0; k < Cn / 2; ++k) {
        int2 t = c2[k]; cidx[2 * k] = t.x; cidx[2 * k + 1] = t.y;
    }
    int nidx[Dn], code[Dn];
    const int2* n2 = (const int2*)(nodes + b * Dn);
    const int2* k2 = (const int2*)(codes + b * Dn);
    #pragma unroll
    for (int k = 0; k < Dn / 2; ++k) {
        int2 t = n2[k]; nidx[2 * k] = t.x; nidx[2 * k + 1] = t.y;
        int2 u = k2[k]; code[2 * k] = u.x; code[2 * k + 1] = u.y;
    }

    const float4* __restrict__ in4 = (const float4*)in_embed;    // 32 f4/row
    const float4* __restrict__ ne4 = (const float4*)node_embed;

    // ---- v = mean of 10 context rows; halves take even/odd c ----
    float4 vs = make_float4(0.f, 0.f, 0.f, 0.f);
    #pragma unroll
    for (int c = 0; c < Cn; c += 2) {
        int idx = hi ? cidx[c + 1] : cidx[c];
        float4 e = in4[(size_t)idx * 32 + sl];
        vs.x += e.x; vs.y += e.y; vs.z += e.z; vs.w += e.w;
    }
    // combine halves: after this both halves hold the full context sum
    vs.x += __shfl_xor(vs.x, 32, 64);
    vs.y += __shfl_xor(vs.y, 32, 64);
    vs.z += __shfl_xor(vs.z, 32, 64);
    vs.w += __shfl_xor(vs.w, 32, 64);
    float4 v;
    v.x = vs.x * (1.0f / Cn); v.y = vs.y * (1.0f / Cn);
    v.z = vs.z * (1.0f / Cn); v.w = vs.w * (1.0f / Cn);

    // ---- 18 dots: half 0 -> even d, half 1 -> odd d (9 each) ----
    float pd[Dn / 2];
    #pragma unroll
    for (int i = 0; i < Dn / 2; ++i) {
        int idx = hi ? nidx[2 * i + 1] : nidx[2 * i];
        float4 u = ne4[(size_t)idx * 32 + sl];
        pd[i] = u.x * v.x + u.y * v.y + u.z * v.z + u.w * v.w;
    }

    // 5-level butterfly within each 32-lane half (masks never cross halves)
    #pragma unroll
    for (int i = 0; i < Dn / 2; ++i) {
        #pragma unroll
        for (int m = 16; m >= 1; m >>= 1)
            pd[i] += __shfl_xor(pd[i], m, 64);
    }

    // ---- loss: 9 transcendental passes, halves do different d in lockstep
    float loss = 0.f;
    #pragma unroll
    for (int i = 0; i < Dn / 2; ++i) {
        int cd = hi ? code[2 * i + 1] : code[2 * i];
        // Literal fp32 reference semantics:
        float s = 1.0f / (1.0f + expf(-pd[i]));
        float p = (cd == 1) ? s : 1.0f - s;
        loss -= logf(p + EPS);
    }
    // half 0 holds even-d terms, half 1 odd-d terms
    loss += __shfl_xor(loss, 32, 64);

    if (lane == 0) out[b] = loss;
}

extern "C" void kernel_launch(void* const* d_in, const int* in_sizes, int n_in,
                              void* d_out, int out_size, void* d_ws, size_t ws_size,
                              hipStream_t stream) {
    const int*   ctx        = (const int*)d_in[0];
    const int*   path_nodes = (const int*)d_in[1];
    const int*   codes      = (const int*)d_in[2];
    const float* in_embed   = (const float*)d_in[3];
    const float* node_embed = (const float*)d_in[4];
    float*       out        = (float*)d_out;

    dim3 grid(Bn / 4);
    dim3 block(256);
    cbow_hs_kernel<<<grid, block, 0, stream>>>(ctx, path_nodes, codes,
                                               in_embed, node_embed, out);
}